// Round 7
// baseline (250.847 us; speedup 1.0000x reference)
//
#include <hip/hip_runtime.h>
#include <math.h>

// FAVOR+ linear attention, segment-normalized — MFMA split-bf16 version.
// All three GEMM phases (U = X@Omega, S = Kp^T V, out = Qp@S) run on
// mfma_f32_16x16x32_bf16 with 3-product bf16 hi/lo emulation (~1e-4 rel err).
// No LDS, no barriers in GEMM kernels; omega pre-packed to fragments once.
//
// N=8192 rows, D=M=DV=128, B=64 segments (batch_seg sorted => contiguous).
//
// ws layout (floats):
//   S      [64*128*128]  per-segment Kp^T V (fully written by k_accum)
//   Ksum   [64*128]      segment sums of Kp (fully written by k_accum)
//   segmax [64]          seg max of rowmax(U_K) clamped >=0 (memset 0)
//   Qp     [8192*128]
//   UK     [8192*128]
//   hK     [8192]
//   OHI    [8192 uints]  omega*INV_D4 bf16-hi packed B-fragments
//   OLO    [8192 uints]  omega*INV_D4 bf16-lo packed B-fragments

#define NROWS 8192
#define DIM   128
#define NSEG  64

#define INV_D4      0.29730177875068026f   // 128^-0.25
#define H_SCALE     0.04419417382415922f   // 1/(2*sqrt(128))
#define INV_SQRT_M  0.08838834764831845f   // 1/sqrt(128)
#define PHI_EPS_F   1e-4f
#define NORM_EPS_F  1e-8f

typedef __attribute__((ext_vector_type(8))) short bf16x8;
typedef __attribute__((ext_vector_type(4))) float f32x4;

// split 8 fp32 into bf16 hi (truncate) + bf16 lo (residual), packed for MFMA
__device__ __forceinline__ void split8(const float v[8], bf16x8& hi, bf16x8& lo)
{
    union UU { unsigned int u[4]; bf16x8 b; };
    UU H, L;
#pragma unroll
    for (int w = 0; w < 4; ++w) {
        const float f0 = v[2 * w], f1 = v[2 * w + 1];
        const unsigned b0 = __float_as_uint(f0), b1 = __float_as_uint(f1);
        const unsigned h0 = b0 & 0xffff0000u, h1 = b1 & 0xffff0000u;
        const float l0 = f0 - __uint_as_float(h0);   // exact residual
        const float l1 = f1 - __uint_as_float(h1);
        H.u[w] = (h0 >> 16) | h1;
        L.u[w] = (__float_as_uint(l0) >> 16) | (__float_as_uint(l1) & 0xffff0000u);
    }
    hi = H.b; lo = L.b;
}

// D += A*B with split operands: Ah*Bh + Ah*Bl + Al*Bh (drop lo*lo)
__device__ __forceinline__ f32x4 mfma3(bf16x8 ah, bf16x8 al, bf16x8 bh,
                                       bf16x8 bl, f32x4 acc)
{
    acc = __builtin_amdgcn_mfma_f32_16x16x32_bf16(ah, bh, acc, 0, 0, 0);
    acc = __builtin_amdgcn_mfma_f32_16x16x32_bf16(ah, bl, acc, 0, 0, 0);
    acc = __builtin_amdgcn_mfma_f32_16x16x32_bf16(al, bh, acc, 0, 0, 0);
    return acc;
}

// ---------------------------------------------------------------------------
// k_pack: omega (fp32 [128][128], k-major) * INV_D4 -> packed bf16 hi/lo
// B-fragments. Fragment (kt,nt): lane l, elem e holds
//   omega[kt*32 + (l>>4)*8 + e][nt*16 + (l&15)].
// uint j = ((kt*8+nt)*64 + lane)*4 + w packs elems (2w, 2w+1).
// ---------------------------------------------------------------------------
__global__ void k_pack(const float* __restrict__ omega,
                       unsigned int* __restrict__ OHI,
                       unsigned int* __restrict__ OLO)
{
    const int j = blockIdx.x * 256 + threadIdx.x;      // 0..8191
    const int w = j & 3, lane = (j >> 2) & 63, nt = (j >> 8) & 7, kt = j >> 11;
    const int e = 2 * w;
    const int k = kt * 32 + (lane >> 4) * 8 + e;
    const int c = nt * 16 + (lane & 15);
    const float f0 = omega[k * DIM + c] * INV_D4;
    const float f1 = omega[(k + 1) * DIM + c] * INV_D4;
    const unsigned b0 = __float_as_uint(f0), b1 = __float_as_uint(f1);
    const unsigned h0 = b0 & 0xffff0000u, h1 = b1 & 0xffff0000u;
    const float l0 = f0 - __uint_as_float(h0);
    const float l1 = f1 - __uint_as_float(h1);
    OHI[j] = (h0 >> 16) | h1;
    OLO[j] = (__float_as_uint(l0) >> 16) | (__float_as_uint(l1) & 0xffff0000u);
}

// ---------------------------------------------------------------------------
// k_phi: per wave, one 16-row strip of U = X @ (omega*INV_D4). 1024 strips
// (512 Q + 512 K), 4 waves/block, grid 256. No LDS, no barriers.
//   Q: Qp = (exp(U - h - rowmax) + eps)/sqrt(m)
//   K: store U (fp32), h; atomicMax positive rowmax into segmax[seg].
// ---------------------------------------------------------------------------
__global__ void k_phi(const float* __restrict__ Q, const float* __restrict__ K,
                      const int* __restrict__ seg,
                      const unsigned int* __restrict__ OHI,
                      const unsigned int* __restrict__ OLO,
                      float* __restrict__ Qp, float* __restrict__ UK,
                      float* __restrict__ hK, int* __restrict__ segmax)
{
    const int tid = threadIdx.x, wid = tid >> 6, l = tid & 63;
    const int g = l >> 4, c16 = l & 15;
    const int sid = blockIdx.x * 4 + wid;              // 0..1023
    const bool isQ = sid < 512;
    const int rowbase = (isQ ? sid : sid - 512) * 16;
    const float* X = isQ ? Q : K;
    const float* xr = X + (size_t)(rowbase + c16) * DIM;  // A-row for this lane

    // A-fragments: lane holds x[row=c16][k = kt*32 + g*8 + e], split hi/lo.
    float hp = 0.f;
    bf16x8 AH[4], AL[4];
#pragma unroll
    for (int kt = 0; kt < 4; ++kt) {
        float v[8];
        const float4 a0 = *(const float4*)&xr[kt * 32 + g * 8];
        const float4 a1 = *(const float4*)&xr[kt * 32 + g * 8 + 4];
        v[0] = a0.x; v[1] = a0.y; v[2] = a0.z; v[3] = a0.w;
        v[4] = a1.x; v[5] = a1.y; v[6] = a1.z; v[7] = a1.w;
#pragma unroll
        for (int e = 0; e < 8; ++e) hp += v[e] * v[e];
        split8(v, AH[kt], AL[kt]);
    }
    hp += __shfl_xor(hp, 16); hp += __shfl_xor(hp, 32);
    const float h_own = hp * H_SCALE;                  // h for row rowbase+c16

    // MFMA: 8 nt-tiles x 4 kt x 3 products
    f32x4 U[8];
#pragma unroll
    for (int nt = 0; nt < 8; ++nt) {
        f32x4 acc = {0.f, 0.f, 0.f, 0.f};
#pragma unroll
        for (int kt = 0; kt < 4; ++kt) {
            const bf16x8 bh = *(const bf16x8*)(OHI + ((size_t)(kt * 8 + nt) * 64 + l) * 4);
            const bf16x8 bl = *(const bf16x8*)(OLO + ((size_t)(kt * 8 + nt) * 64 + l) * 4);
            acc = mfma3(AH[kt], AL[kt], bh, bl, acc);
        }
        U[nt] = acc;
    }

    // epilogue: C-layout row = g*4+reg, col = nt*16 + c16
    float hreg[4], mx[4];
#pragma unroll
    for (int r = 0; r < 4; ++r) {
        hreg[r] = __shfl(h_own, g * 4 + r);            // h of row g*4+r
        float m = U[0][r];
#pragma unroll
        for (int nt = 1; nt < 8; ++nt) m = fmaxf(m, U[nt][r]);
        m = fmaxf(m, __shfl_xor(m, 1)); m = fmaxf(m, __shfl_xor(m, 2));
        m = fmaxf(m, __shfl_xor(m, 4)); m = fmaxf(m, __shfl_xor(m, 8));
        mx[r] = m;                                     // rowmax over 128 cols
    }

    if (isQ) {
#pragma unroll
        for (int r = 0; r < 4; ++r) {
            const float b = hreg[r] + mx[r];
            float* orow = Qp + (size_t)(rowbase + g * 4 + r) * DIM + c16;
#pragma unroll
            for (int nt = 0; nt < 8; ++nt)
                orow[nt * 16] = (__expf(U[nt][r] - b) + PHI_EPS_F) * INV_SQRT_M;
        }
    } else {
#pragma unroll
        for (int r = 0; r < 4; ++r) {
            float* orow = UK + (size_t)(rowbase + g * 4 + r) * DIM + c16;
#pragma unroll
            for (int nt = 0; nt < 8; ++nt) orow[nt * 16] = U[nt][r];
        }
        if (l < 16) hK[rowbase + l] = h_own;
        if (c16 == 0) {
#pragma unroll
            for (int r = 0; r < 4; ++r) {
                if (mx[r] > 0.f)   // zero-init implements max(.,0) clamp
                    atomicMax(&segmax[seg[rowbase + g * 4 + r]],
                              __float_as_int(mx[r]));
            }
        }
    }
}

// ---------------------------------------------------------------------------
// k_accum: per wave, one (seg, 16-m-strip) of S = Kp^T V over all seg rows.
// Grid 64*8 = 512 blocks x 64 threads. Kp from UK/hK/segmax on the fly.
// Ksum produced in-register (lane partial -> shfl reduce). No atomics.
// ---------------------------------------------------------------------------
__global__ void k_accum(const float* __restrict__ UK,
                        const float* __restrict__ hK,
                        const float* __restrict__ V,
                        const int* __restrict__ seg,
                        const float* __restrict__ segmaxf,
                        float* __restrict__ S, float* __restrict__ Ksum)
{
    const int l = threadIdx.x, g = l >> 4, c16 = l & 15;
    const int sg = blockIdx.x >> 3, ms = blockIdx.x & 7, mbase = ms * 16;

    int start, end;
    {
        int a = 0, b = NROWS;
        while (a < b) { int m = (a + b) >> 1; if (seg[m] < sg) a = m + 1; else b = m; }
        start = a; b = NROWS;
        while (a < b) { int m = (a + b) >> 1; if (seg[m] < sg + 1) a = m + 1; else b = m; }
        end = a;
    }
    const float smax = segmaxf[sg];

    f32x4 acc[8];
#pragma unroll
    for (int nt = 0; nt < 8; ++nt) acc[nt] = (f32x4){0.f, 0.f, 0.f, 0.f};
    float ksp = 0.f;

    for (int j = start; j < end; j += 32) {
        // A-fragment: Kp^T — lane holds m = mbase+c16, k-rows j + g*8 + e
        float kp[8];
#pragma unroll
        for (int e = 0; e < 8; ++e) {
            const int r = j + g * 8 + e;
            float f = 0.f;
            if (r < end) {
                const float u = UK[(size_t)r * DIM + mbase + c16];
                f = (__expf(u - hK[r] - smax) + PHI_EPS_F) * INV_SQRT_M;
            }
            kp[e] = f; ksp += f;
        }
        bf16x8 Ah, Al; split8(kp, Ah, Al);
#pragma unroll
        for (int nt = 0; nt < 8; ++nt) {
            float vv[8];
#pragma unroll
            for (int e = 0; e < 8; ++e) {
                const int r = j + g * 8 + e;
                vv[e] = (r < end) ? V[(size_t)r * DIM + nt * 16 + c16] : 0.f;
            }
            bf16x8 Bh, Bl; split8(vv, Bh, Bl);
            acc[nt] = mfma3(Ah, Al, Bh, Bl, acc[nt]);
        }
    }

    float* Ss = S + (size_t)sg * DIM * DIM;
#pragma unroll
    for (int nt = 0; nt < 8; ++nt)
#pragma unroll
        for (int r = 0; r < 4; ++r)
            Ss[(mbase + g * 4 + r) * DIM + nt * 16 + c16] = acc[nt][r];

    // Ksum[m] for m = mbase + c16: reduce lane partials over g
    ksp += __shfl_xor(ksp, 16); ksp += __shfl_xor(ksp, 32);
    if (l < 16) Ksum[sg * DIM + mbase + l] = ksp;
}

// ---------------------------------------------------------------------------
// k_out: per wave, one 16-row strip: out = (Qp @ S[seg]) / (Qp.Ksum[seg]+eps).
// Grid 512 x 64. Strips spanning a segment boundary loop the segments
// present with masked stores (S of absent/empty segs is all-zero, harmless).
// ---------------------------------------------------------------------------
__global__ void k_out(const float* __restrict__ Qp, const float* __restrict__ S,
                      const float* __restrict__ Ksum, const int* __restrict__ seg,
                      float* __restrict__ out)
{
    const int l = threadIdx.x, g = l >> 4, c16 = l & 15;
    const int rowbase = blockIdx.x * 16;
    const int rowl = rowbase + c16;
    const int sgl = seg[rowl];

    // A-fragments from Qp + norm partial (fp32 exact)
    bf16x8 AH[4], AL[4];
    float np = 0.f;
    const float* qrow = Qp + (size_t)rowl * DIM;
#pragma unroll
    for (int kt = 0; kt < 4; ++kt) {
        float v[8];
        const float4 a0 = *(const float4*)&qrow[kt * 32 + g * 8];
        const float4 a1 = *(const float4*)&qrow[kt * 32 + g * 8 + 4];
        v[0] = a0.x; v[1] = a0.y; v[2] = a0.z; v[3] = a0.w;
        v[4] = a1.x; v[5] = a1.y; v[6] = a1.z; v[7] = a1.w;
        const float* ks = Ksum + sgl * DIM + kt * 32 + g * 8;
#pragma unroll
        for (int e = 0; e < 8; ++e) np += v[e] * ks[e];
        split8(v, AH[kt], AL[kt]);
    }
    np += __shfl_xor(np, 16); np += __shfl_xor(np, 32);  // norm for row c16

    int segr[4]; float nrm[4];
#pragma unroll
    for (int r = 0; r < 4; ++r) {
        segr[r] = seg[rowbase + g * 4 + r];
        nrm[r] = __shfl(np, g * 4 + r) + NORM_EPS_F;
    }

    const int s0 = seg[rowbase], s1 = seg[rowbase + 15];
    for (int sgi = s0; sgi <= s1; ++sgi) {
        const float* Ss = S + (size_t)sgi * DIM * DIM;
        f32x4 acc[8];
#pragma unroll
        for (int nt = 0; nt < 8; ++nt) acc[nt] = (f32x4){0.f, 0.f, 0.f, 0.f};
#pragma unroll
        for (int kt = 0; kt < 4; ++kt) {
            float bvals[8][8];   // [nt][e] staged per kt
#pragma unroll
            for (int nt = 0; nt < 8; ++nt)
#pragma unroll
                for (int e = 0; e < 8; ++e)
                    bvals[nt][e] = Ss[(size_t)(kt * 32 + g * 8 + e) * DIM + nt * 16 + c16];
#pragma unroll
            for (int nt = 0; nt < 8; ++nt) {
                bf16x8 Bh, Bl; split8(bvals[nt], Bh, Bl);
                acc[nt] = mfma3(AH[kt], AL[kt], Bh, Bl, acc[nt]);
            }
        }
#pragma unroll
        for (int nt = 0; nt < 8; ++nt)
#pragma unroll
            for (int r = 0; r < 4; ++r)
                if (segr[r] == sgi)
                    out[(size_t)(rowbase + g * 4 + r) * DIM + nt * 16 + c16]
                        = acc[nt][r] / nrm[r];
    }
}

// ---------------------------------------------------------------------------
extern "C" void kernel_launch(void* const* d_in, const int* in_sizes, int n_in,
                              void* d_out, int out_size, void* d_ws, size_t ws_size,
                              hipStream_t stream)
{
    const float* Q     = (const float*)d_in[0];
    const float* K     = (const float*)d_in[1];
    const float* V     = (const float*)d_in[2];
    const float* omega = (const float*)d_in[3];
    const int*   seg   = (const int*)d_in[4];
    float* out = (float*)d_out;

    float* ws      = (float*)d_ws;
    float* S       = ws;
    float* Ksum    = S + (size_t)NSEG * DIM * DIM;
    float* segmaxf = Ksum + NSEG * DIM;
    float* Qp      = segmaxf + NSEG;
    float* UK      = Qp + (size_t)NROWS * DIM;
    float* hK      = UK + (size_t)NROWS * DIM;
    unsigned int* OHI = (unsigned int*)(hK + NROWS);
    unsigned int* OLO = OHI + 8192;

    hipMemsetAsync(segmaxf, 0, NSEG * sizeof(float), stream);

    hipLaunchKernelGGL(k_pack, dim3(32), dim3(256), 0, stream, omega, OHI, OLO);
    hipLaunchKernelGGL(k_phi, dim3(256), dim3(256), 0, stream,
                       Q, K, seg, OHI, OLO, Qp, UK, hK, (int*)segmaxf);
    hipLaunchKernelGGL(k_accum, dim3(512), dim3(64), 0, stream,
                       UK, hK, V, seg, segmaxf, S, Ksum);
    hipLaunchKernelGGL(k_out, dim3(512), dim3(64), 0, stream,
                       Qp, S, Ksum, seg, out);
}

// Round 8
// 164.125 us; speedup vs baseline: 1.5284x; 1.5284x over previous
//
#include <hip/hip_runtime.h>
#include <math.h>

// FAVOR+ linear attention, segment-normalized. fp32 VALU path.
// N=8192 rows, D=M=DV=128, B=64 segments (batch_seg sorted => contiguous).
//
// Round-8 structure: k_phi/k_out stream omega/S from L2 (broadcast-friendly
// 512B row reads), stage only the 16 input rows in LDS (8 KB) -> 4+ blocks/CU.
// k_accum is the round-6 v2 kernel (measured out of top-5), kept identical.
//
// ws layout (floats):
//   S      [64*128*128]  per-segment Kp^T V (fully written by k_accum)
//   Ksum   [64*128]      segment sums of Kp (fully written by k_accum)
//   segmax [64]          seg max of rowmax(U_K) clamped >=0 (memset 0)
//   Qp     [8192*128]
//   UK     [8192*128]
//   hK     [8192]

#define NROWS 8192
#define DIM   128
#define NSEG  64

#define INV_D4      0.29730177875068026f   // 128^-0.25
#define INV_SQRT_M  0.08838834764831845f   // 1/sqrt(128)
#define PHI_EPS_F   1e-4f
#define NORM_EPS_F  1e-8f
// h = sum(x^2)/(2*sqrt(128)) = 0.5 * sum((x*INV_D4)^2)  (exact fold)

// ---------------------------------------------------------------------------
// k_phi: U = (x*INV_D4) @ omega. Grid 1024 blocks x 256 thr; block = 16 rows
// (first 512 blocks Q, rest K). LDS: only the 16 scaled input rows (8 KB).
// omega streamed from global: lane cl reads omega[d][cl*4..3] -> 512B
// broadcast rows, L1/L2 resident. Lane owns 2 rows x 4 cols.
//   Q: Qp = (exp(U - h - rowmax) + eps)/sqrt(m)
//   K: store U (fp32), h; atomicMax positive rowmax into segmax[seg].
// ---------------------------------------------------------------------------
__global__ __launch_bounds__(256, 4) void k_phi(
    const float* __restrict__ Q, const float* __restrict__ K,
    const float* __restrict__ omega, const int* __restrict__ seg,
    float* __restrict__ Qp, float* __restrict__ UK,
    float* __restrict__ hK, int* __restrict__ segmax)
{
    __shared__ float xs[16][DIM];    // 8 KB

    const int t = threadIdx.x;
    const int bid = blockIdx.x;
    const bool isQ = bid < 512;
    const int rowbase = (isQ ? bid : bid - 512) * 16;
    const float* X = (isQ ? Q : K) + (size_t)rowbase * DIM;

    // stage 16 rows scaled by INV_D4 (512 float4, 2 per thread, coalesced)
    {
        const float4* xg = (const float4*)X;
        float4* xd = (float4*)&xs[0][0];
#pragma unroll
        for (int s = 0; s < 2; ++s) {
            float4 v = xg[t + s * 256];
            v.x *= INV_D4; v.y *= INV_D4; v.z *= INV_D4; v.w *= INV_D4;
            xd[t + s * 256] = v;
        }
    }
    __syncthreads();

    const int w = t >> 6, lane = t & 63;
    const int rg = lane >> 5, cl = lane & 31;
    const int rA = w * 4 + rg * 2, rB = rA + 1;   // block-local rows

    // h for rows rA,rB: 0.5 * sum(xs^2), reduced over the 32-lane group
    float hA, hB;
    {
        const float4 a = *(const float4*)&xs[rA][cl * 4];
        const float4 b = *(const float4*)&xs[rB][cl * 4];
        float pa = a.x * a.x + a.y * a.y + a.z * a.z + a.w * a.w;
        float pb = b.x * b.x + b.y * b.y + b.z * b.z + b.w * b.w;
#pragma unroll
        for (int m = 1; m < 32; m <<= 1) {
            pa += __shfl_xor(pa, m, 64);
            pb += __shfl_xor(pb, m, 64);
        }
        hA = 0.5f * pa; hB = 0.5f * pb;
    }

    float4 accA = make_float4(0.f, 0.f, 0.f, 0.f);
    float4 accB = make_float4(0.f, 0.f, 0.f, 0.f);

#pragma unroll 2
    for (int d = 0; d < DIM; d += 4) {
        const float4 o0 = *(const float4*)&omega[(size_t)(d + 0) * DIM + cl * 4];
        const float4 o1 = *(const float4*)&omega[(size_t)(d + 1) * DIM + cl * 4];
        const float4 o2 = *(const float4*)&omega[(size_t)(d + 2) * DIM + cl * 4];
        const float4 o3 = *(const float4*)&omega[(size_t)(d + 3) * DIM + cl * 4];
        const float4 xa = *(const float4*)&xs[rA][d];   // broadcast reads
        const float4 xb = *(const float4*)&xs[rB][d];
        accA.x = fmaf(xa.x, o0.x, fmaf(xa.y, o1.x, fmaf(xa.z, o2.x, fmaf(xa.w, o3.x, accA.x))));
        accA.y = fmaf(xa.x, o0.y, fmaf(xa.y, o1.y, fmaf(xa.z, o2.y, fmaf(xa.w, o3.y, accA.y))));
        accA.z = fmaf(xa.x, o0.z, fmaf(xa.y, o1.z, fmaf(xa.z, o2.z, fmaf(xa.w, o3.z, accA.z))));
        accA.w = fmaf(xa.x, o0.w, fmaf(xa.y, o1.w, fmaf(xa.z, o2.w, fmaf(xa.w, o3.w, accA.w))));
        accB.x = fmaf(xb.x, o0.x, fmaf(xb.y, o1.x, fmaf(xb.z, o2.x, fmaf(xb.w, o3.x, accB.x))));
        accB.y = fmaf(xb.x, o0.y, fmaf(xb.y, o1.y, fmaf(xb.z, o2.y, fmaf(xb.w, o3.y, accB.y))));
        accB.z = fmaf(xb.x, o0.z, fmaf(xb.y, o1.z, fmaf(xb.z, o2.z, fmaf(xb.w, o3.z, accB.z))));
        accB.w = fmaf(xb.x, o0.w, fmaf(xb.y, o1.w, fmaf(xb.z, o2.w, fmaf(xb.w, o3.w, accB.w))));
    }

    // rowmax over 128 cols (4 regs + 32-lane reduce)
    float mA = fmaxf(fmaxf(accA.x, accA.y), fmaxf(accA.z, accA.w));
    float mB = fmaxf(fmaxf(accB.x, accB.y), fmaxf(accB.z, accB.w));
#pragma unroll
    for (int m = 1; m < 32; m <<= 1) {
        mA = fmaxf(mA, __shfl_xor(mA, m, 64));
        mB = fmaxf(mB, __shfl_xor(mB, m, 64));
    }

    const int gA = rowbase + rA, gB = rowbase + rB;
    if (isQ) {
        const float bA = hA + mA, bB = hB + mB;
        float4 eA, eB;
        eA.x = (__expf(accA.x - bA) + PHI_EPS_F) * INV_SQRT_M;
        eA.y = (__expf(accA.y - bA) + PHI_EPS_F) * INV_SQRT_M;
        eA.z = (__expf(accA.z - bA) + PHI_EPS_F) * INV_SQRT_M;
        eA.w = (__expf(accA.w - bA) + PHI_EPS_F) * INV_SQRT_M;
        eB.x = (__expf(accB.x - bB) + PHI_EPS_F) * INV_SQRT_M;
        eB.y = (__expf(accB.y - bB) + PHI_EPS_F) * INV_SQRT_M;
        eB.z = (__expf(accB.z - bB) + PHI_EPS_F) * INV_SQRT_M;
        eB.w = (__expf(accB.w - bB) + PHI_EPS_F) * INV_SQRT_M;
        *(float4*)&Qp[(size_t)gA * DIM + cl * 4] = eA;
        *(float4*)&Qp[(size_t)gB * DIM + cl * 4] = eB;
    } else {
        *(float4*)&UK[(size_t)gA * DIM + cl * 4] = accA;
        *(float4*)&UK[(size_t)gB * DIM + cl * 4] = accB;
        if (cl == 0) {
            hK[gA] = hA; hK[gB] = hB;
            if (mA > 0.f) atomicMax(&segmax[seg[gA]], __float_as_int(mA));
            if (mB > 0.f) atomicMax(&segmax[seg[gB]], __float_as_int(mB));
        }
    }
}

// ---------------------------------------------------------------------------
// k_accum (round-6 v2, unchanged): per (seg, 32x32 tile) block over all seg
// rows. Grid 1024, direct stores, no atomics. Ksum via LDS column reduce.
// ---------------------------------------------------------------------------
__global__ __launch_bounds__(256, 4) void k_accum(
    const float* __restrict__ UK, const float* __restrict__ hK,
    const float* __restrict__ V, const int* __restrict__ seg,
    const float* __restrict__ segmaxf,
    float* __restrict__ S, float* __restrict__ Ksum)
{
    __shared__ float kp[32][32];
    __shared__ float vv[32][32];

    const int t = threadIdx.x;
    const int sid  = blockIdx.x >> 4;
    const int tile = blockIdx.x & 15;
    const int tm = (tile >> 2) * 32;
    const int tv = (tile & 3) * 32;

    int start, end;
    {
        int a = 0, b = NROWS;
        while (a < b) { int m = (a + b) >> 1; if (seg[m] < sid) a = m + 1; else b = m; }
        start = a; b = NROWS;
        while (a < b) { int m = (a + b) >> 1; if (seg[m] < sid + 1) a = m + 1; else b = m; }
        end = a;
    }

    const float smax = segmaxf[sid];
    const int rs = t >> 3;
    const int cs = (t & 7) * 4;
    const int ty = t >> 4;
    const int tx = t & 15;

    float a00 = 0.f, a01 = 0.f, a10 = 0.f, a11 = 0.f;
    float4 ksl = make_float4(0.f, 0.f, 0.f, 0.f);

    for (int j = start; j < end; j += 32) {
        const int row = j + rs;
        float4 kpv = make_float4(0.f, 0.f, 0.f, 0.f);
        float4 vvv = make_float4(0.f, 0.f, 0.f, 0.f);
        if (row < end) {
            const float4 u = *(const float4*)&UK[(size_t)row * DIM + tm + cs];
            const float h = hK[row] + smax;
            kpv.x = (__expf(u.x - h) + PHI_EPS_F) * INV_SQRT_M;
            kpv.y = (__expf(u.y - h) + PHI_EPS_F) * INV_SQRT_M;
            kpv.z = (__expf(u.z - h) + PHI_EPS_F) * INV_SQRT_M;
            kpv.w = (__expf(u.w - h) + PHI_EPS_F) * INV_SQRT_M;
            vvv = *(const float4*)&V[(size_t)row * DIM + tv + cs];
        }
        __syncthreads();
        *(float4*)&kp[rs][cs] = kpv;
        *(float4*)&vv[rs][cs] = vvv;
        ksl.x += kpv.x; ksl.y += kpv.y; ksl.z += kpv.z; ksl.w += kpv.w;
        __syncthreads();
#pragma unroll
        for (int k = 0; k < 32; ++k) {
            const float2 ka = *(const float2*)&kp[k][ty * 2];
            const float2 vb = *(const float2*)&vv[k][tx * 2];
            a00 = fmaf(ka.x, vb.x, a00);
            a01 = fmaf(ka.x, vb.y, a01);
            a10 = fmaf(ka.y, vb.x, a10);
            a11 = fmaf(ka.y, vb.y, a11);
        }
    }

    float* Sseg = S + (size_t)sid * DIM * DIM;
    {
        float2 r0; r0.x = a00; r0.y = a01;
        float2 r1; r1.x = a10; r1.y = a11;
        *(float2*)&Sseg[(tm + 2 * ty + 0) * DIM + tv + 2 * tx] = r0;
        *(float2*)&Sseg[(tm + 2 * ty + 1) * DIM + tv + 2 * tx] = r1;
    }

    __syncthreads();
    *(float4*)&kp[rs][cs] = ksl;
    __syncthreads();
    if (tv == 0 && t < 32) {
        float s = 0.f;
#pragma unroll
        for (int r = 0; r < 32; ++r) s += kp[r][t];
        Ksum[sid * DIM + tm + t] = s;
    }
}

// ---------------------------------------------------------------------------
// k_out: out_i = (Qp_i @ S[seg_i]) / (Qp_i . Ksum[seg_i] + eps).
// Grid 512 x 256 thr; block = 16 rows; LDS only the 16 Qp rows (8 KB).
// S streamed from global per row (512B broadcast rows, L2-resident);
// per-row S base handles segment boundaries inside a strip uniformly.
// ---------------------------------------------------------------------------
__global__ __launch_bounds__(256, 4) void k_out(
    const float* __restrict__ Qp, const float* __restrict__ S,
    const float* __restrict__ Ksum, const int* __restrict__ seg,
    float* __restrict__ out)
{
    __shared__ float qs[16][DIM];    // 8 KB

    const int t = threadIdx.x;
    const int rowbase = blockIdx.x * 16;

    {
        const float4* xg = (const float4*)(Qp + (size_t)rowbase * DIM);
        float4* xd = (float4*)&qs[0][0];
#pragma unroll
        for (int s = 0; s < 2; ++s) xd[t + s * 256] = xg[t + s * 256];
    }
    __syncthreads();

    const int w = t >> 6, lane = t & 63;
    const int rg = lane >> 5, cl = lane & 31;
    const int rA = w * 4 + rg * 2, rB = rA + 1;
    const int gA = rowbase + rA, gB = rowbase + rB;
    const int sA = seg[gA], sB = seg[gB];
    const float* SA = S + (size_t)sA * DIM * DIM;
    const float* SB = S + (size_t)sB * DIM * DIM;

    // norms: dot(Qp_row, Ksum[seg_row]) via 4-elem partial + 32-lane reduce
    float nA, nB;
    {
        const float4 qa = *(const float4*)&qs[rA][cl * 4];
        const float4 qb = *(const float4*)&qs[rB][cl * 4];
        const float4 ka = *(const float4*)&Ksum[sA * DIM + cl * 4];
        const float4 kb = *(const float4*)&Ksum[sB * DIM + cl * 4];
        float pa = qa.x * ka.x + qa.y * ka.y + qa.z * ka.z + qa.w * ka.w;
        float pb = qb.x * kb.x + qb.y * kb.y + qb.z * kb.z + qb.w * kb.w;
#pragma unroll
        for (int m = 1; m < 32; m <<= 1) {
            pa += __shfl_xor(pa, m, 64);
            pb += __shfl_xor(pb, m, 64);
        }
        nA = pa + NORM_EPS_F; nB = pb + NORM_EPS_F;
    }

    float4 accA = make_float4(0.f, 0.f, 0.f, 0.f);
    float4 accB = make_float4(0.f, 0.f, 0.f, 0.f);

#pragma unroll 2
    for (int m = 0; m < DIM; m += 4) {
        const float4 qa = *(const float4*)&qs[rA][m];
        const float4 qb = *(const float4*)&qs[rB][m];
        const float4 a0 = *(const float4*)&SA[(size_t)(m + 0) * DIM + cl * 4];
        const float4 a1 = *(const float4*)&SA[(size_t)(m + 1) * DIM + cl * 4];
        const float4 a2 = *(const float4*)&SA[(size_t)(m + 2) * DIM + cl * 4];
        const float4 a3 = *(const float4*)&SA[(size_t)(m + 3) * DIM + cl * 4];
        const float4 b0 = *(const float4*)&SB[(size_t)(m + 0) * DIM + cl * 4];
        const float4 b1 = *(const float4*)&SB[(size_t)(m + 1) * DIM + cl * 4];
        const float4 b2 = *(const float4*)&SB[(size_t)(m + 2) * DIM + cl * 4];
        const float4 b3 = *(const float4*)&SB[(size_t)(m + 3) * DIM + cl * 4];
        accA.x = fmaf(qa.x, a0.x, fmaf(qa.y, a1.x, fmaf(qa.z, a2.x, fmaf(qa.w, a3.x, accA.x))));
        accA.y = fmaf(qa.x, a0.y, fmaf(qa.y, a1.y, fmaf(qa.z, a2.y, fmaf(qa.w, a3.y, accA.y))));
        accA.z = fmaf(qa.x, a0.z, fmaf(qa.y, a1.z, fmaf(qa.z, a2.z, fmaf(qa.w, a3.z, accA.z))));
        accA.w = fmaf(qa.x, a0.w, fmaf(qa.y, a1.w, fmaf(qa.z, a2.w, fmaf(qa.w, a3.w, accA.w))));
        accB.x = fmaf(qb.x, b0.x, fmaf(qb.y, b1.x, fmaf(qb.z, b2.x, fmaf(qb.w, b3.x, accB.x))));
        accB.y = fmaf(qb.x, b0.y, fmaf(qb.y, b1.y, fmaf(qb.z, b2.y, fmaf(qb.w, b3.y, accB.y))));
        accB.z = fmaf(qb.x, b0.z, fmaf(qb.y, b1.z, fmaf(qb.z, b2.z, fmaf(qb.w, b3.z, accB.z))));
        accB.w = fmaf(qb.x, b0.w, fmaf(qb.y, b1.w, fmaf(qb.z, b2.w, fmaf(qb.w, b3.w, accB.w))));
    }

    const float iA = 1.0f / nA, iB = 1.0f / nB;
    float4 oA, oB;
    oA.x = accA.x * iA; oA.y = accA.y * iA; oA.z = accA.z * iA; oA.w = accA.w * iA;
    oB.x = accB.x * iB; oB.y = accB.y * iB; oB.z = accB.z * iB; oB.w = accB.w * iB;
    *(float4*)&out[(size_t)gA * DIM + cl * 4] = oA;
    *(float4*)&out[(size_t)gB * DIM + cl * 4] = oB;
}

// ---------------------------------------------------------------------------
extern "C" void kernel_launch(void* const* d_in, const int* in_sizes, int n_in,
                              void* d_out, int out_size, void* d_ws, size_t ws_size,
                              hipStream_t stream)
{
    const float* Q     = (const float*)d_in[0];
    const float* K     = (const float*)d_in[1];
    const float* V     = (const float*)d_in[2];
    const float* omega = (const float*)d_in[3];
    const int*   seg   = (const int*)d_in[4];
    float* out = (float*)d_out;

    float* ws      = (float*)d_ws;
    float* S       = ws;
    float* Ksum    = S + (size_t)NSEG * DIM * DIM;
    float* segmaxf = Ksum + NSEG * DIM;
    float* Qp      = segmaxf + NSEG;
    float* UK      = Qp + (size_t)NROWS * DIM;
    float* hK      = UK + (size_t)NROWS * DIM;

    hipMemsetAsync(segmaxf, 0, NSEG * sizeof(float), stream);

    hipLaunchKernelGGL(k_phi, dim3(1024), dim3(256), 0, stream,
                       Q, K, omega, seg, Qp, UK, hK, (int*)segmaxf);
    hipLaunchKernelGGL(k_accum, dim3(NSEG * 16), dim3(256), 0, stream,
                       UK, hK, V, seg, segmaxf, S, Ksum);
    hipLaunchKernelGGL(k_out, dim3(512), dim3(256), 0, stream,
                       Qp, S, Ksum, seg, out);
}